// Round 1
// baseline (1992.308 us; speedup 1.0000x reference)
//
#include <hip/hip_runtime.h>
#include <stdint.h>

#define D_MODEL 768
#define N_TOK   2048
#define SEQLEN  1024
#define N_HEAD  12
#define HEAD_D  64
#define N_LAYER 2
#define D_FF    3072
#define N_VOCAB 50257
#define D_QKV   2304

typedef unsigned short u16;
typedef __attribute__((ext_vector_type(8))) short bf16x8;   // 8 bf16 = 4 VGPRs
typedef __attribute__((ext_vector_type(4))) float f32x4;

__device__ __forceinline__ u16 f2b(float f) {               // fp32 -> bf16 RNE
  uint32_t u = __float_as_uint(f);
  return (u16)((u + 0x7fffu + ((u >> 16) & 1u)) >> 16);
}
__device__ __forceinline__ float b2f(u16 h) {
  return __uint_as_float(((uint32_t)h) << 16);
}

__device__ __forceinline__ void gl2lds16(const void* g, void* l) {
  __builtin_amdgcn_global_load_lds(
      (const __attribute__((address_space(1))) uint32_t*)g,
      (__attribute__((address_space(3))) uint32_t*)l, 16, 0, 0);
}

// ---------------- fp32 -> bf16 bulk convert ----------------
__global__ __launch_bounds__(256) void cvt_k(const float* __restrict__ s,
                                             u16* __restrict__ d, int n4) {
  int i = blockIdx.x * 256 + threadIdx.x;
  if (i >= n4) return;
  float4 v = ((const float4*)s)[i];
  ushort4 o;
  o.x = f2b(v.x); o.y = f2b(v.y); o.z = f2b(v.z); o.w = f2b(v.w);
  ((ushort4*)d)[i] = o;
}

// ---------------- embedding gather ----------------
__global__ __launch_bounds__(256) void embed_k(const int* __restrict__ ids,
                                               const float* __restrict__ emb,
                                               const float* __restrict__ pos,
                                               float* __restrict__ R) {
  int t = blockIdx.x;
  int id = ids[t];
  int s = t & (SEQLEN - 1);
  const float* e = emb + (size_t)id * D_MODEL;
  const float* pp = pos + (size_t)s * D_MODEL;
  float* r = R + (size_t)t * D_MODEL;
  for (int i = threadIdx.x; i < D_MODEL; i += 256) r[i] = e[i] + pp[i];
}

// ---------------- layernorm: fp32 in -> bf16 out ----------------
// faithful to ref: y = w*(x-m)/(sqrt(var)+eps)+b, var biased (/D)
__global__ __launch_bounds__(256) void ln_k(const float* __restrict__ X,
                                            const float* __restrict__ w,
                                            const float* __restrict__ b,
                                            u16* __restrict__ out) {
  int t = blockIdx.x;
  const float* x = X + (size_t)t * D_MODEL;
  float v0 = x[threadIdx.x], v1 = x[threadIdx.x + 256], v2 = x[threadIdx.x + 512];
  float s = v0 + v1 + v2;
  float s2 = v0 * v0 + v1 * v1 + v2 * v2;
  for (int off = 32; off; off >>= 1) {
    s  += __shfl_xor(s, off);
    s2 += __shfl_xor(s2, off);
  }
  __shared__ float rs[4], rq[4];
  int wv = threadIdx.x >> 6, ln = threadIdx.x & 63;
  if (ln == 0) { rs[wv] = s; rq[wv] = s2; }
  __syncthreads();
  s  = rs[0] + rs[1] + rs[2] + rs[3];
  s2 = rq[0] + rq[1] + rq[2] + rq[3];
  const float inv_d = 1.0f / (float)D_MODEL;
  float m = s * inv_d;
  float var = fmaxf(s2 * inv_d - m * m, 0.0f);
  float inv = 1.0f / (sqrtf(var) + 1e-5f);
  u16* o = out + (size_t)t * D_MODEL;
  int d0 = threadIdx.x;
  o[d0]       = f2b(w[d0]       * ((v0 - m) * inv) + b[d0]);
  o[d0 + 256] = f2b(w[d0 + 256] * ((v1 - m) * inv) + b[d0 + 256]);
  o[d0 + 512] = f2b(w[d0 + 512] * ((v2 - m) * inv) + b[d0 + 512]);
}

// ---------------- bf16 NT GEMM: C[M,N] = A[M,K] @ B[N,K]^T + bias (+res)(gelu) ----
// m97 structure: 128x128 tile, BK=32, 4 waves each 64x64, global_load_lds w=16.
template <bool GELU, bool RES, bool OUT_BF16>
__global__ __launch_bounds__(256) void gemm_bt(
    const u16* __restrict__ A, const u16* __restrict__ B,
    const float* __restrict__ bias, const float* __restrict__ resid,
    void* __restrict__ Cout, int M, int N, int K) {
  __shared__ u16 As[128 * 32];
  __shared__ u16 Bs[128 * 32];
  const int t = threadIdx.x;
  const int wv = t >> 6, ln = t & 63;
  const int wm = wv >> 1, wn = wv & 1;
  const int l15 = ln & 15, lq = ln >> 4;
  const int bm0 = blockIdx.y * 128;
  const int bn0 = blockIdx.x * 128;

  // staging: wave wv handles 2 calls; lane adds +16B automatically in HW
  const int srow = wv * 32 + (ln >> 2);
  const int scol = (ln & 3) * 8;
  const u16* aS0 = A + (size_t)(bm0 + srow) * K + scol;
  const u16* aS1 = A + (size_t)(bm0 + srow + 16) * K + scol;
  int br0 = bn0 + srow;      if (br0 > N - 1) br0 = N - 1;
  int br1 = bn0 + srow + 16; if (br1 > N - 1) br1 = N - 1;
  const u16* bS0 = B + (size_t)br0 * K + scol;
  const u16* bS1 = B + (size_t)br1 * K + scol;
  u16* aD0 = &As[wv * 1024];
  u16* aD1 = &As[wv * 1024 + 512];
  u16* bD0 = &Bs[wv * 1024];
  u16* bD1 = &Bs[wv * 1024 + 512];

  f32x4 acc[4][4] = {};

  for (int kt = 0; kt < K; kt += 32) {
    gl2lds16(aS0 + kt, aD0);
    gl2lds16(aS1 + kt, aD1);
    gl2lds16(bS0 + kt, bD0);
    gl2lds16(bS1 + kt, bD1);
    __syncthreads();
    bf16x8 af[4], bfr[4];
#pragma unroll
    for (int mi = 0; mi < 4; ++mi)
      af[mi] = *(const bf16x8*)&As[(wm * 64 + mi * 16 + l15) * 32 + lq * 8];
#pragma unroll
    for (int ni = 0; ni < 4; ++ni)
      bfr[ni] = *(const bf16x8*)&Bs[(wn * 64 + ni * 16 + l15) * 32 + lq * 8];
#pragma unroll
    for (int mi = 0; mi < 4; ++mi)
#pragma unroll
      for (int ni = 0; ni < 4; ++ni)
        acc[mi][ni] = __builtin_amdgcn_mfma_f32_16x16x32_bf16(af[mi], bfr[ni],
                                                              acc[mi][ni], 0, 0, 0);
    __syncthreads();
  }

  // epilogue: C/D layout col=lane&15, row=quad*4+reg (verified m89/m91)
#pragma unroll
  for (int ni = 0; ni < 4; ++ni) {
    int col = bn0 + wn * 64 + ni * 16 + l15;
    if (col >= N) continue;
    float bv = bias[col];
#pragma unroll
    for (int mi = 0; mi < 4; ++mi) {
#pragma unroll
      for (int r = 0; r < 4; ++r) {
        int row = bm0 + wm * 64 + mi * 16 + lq * 4 + r;
        float v = acc[mi][ni][r] + bv;
        if constexpr (RES) v += resid[(size_t)row * N + col];
        if constexpr (GELU) v = 0.5f * v * (1.0f + erff(v * 0.70710678118f));
        if constexpr (OUT_BF16) ((u16*)Cout)[(size_t)row * N + col] = f2b(v);
        else                    ((float*)Cout)[(size_t)row * N + col] = v;
      }
    }
  }
}

// ---------------- flash attention: 4 q-rows/block, K/V chunks of 64 in LDS ----
__global__ __launch_bounds__(256) void attn_k(const u16* __restrict__ qkv,
                                              u16* __restrict__ out) {
  const int bh = blockIdx.y;
  const int bb = bh / N_HEAD, h = bh % N_HEAD;
  const int qblk = blockIdx.x;               // 0..255
  const int wv = threadIdx.x >> 6, ln = threadIdx.x & 63;
  const int qrow = qblk * 4 + wv;

  __shared__ float Kl[64][65];   // pad -> (l+d)%32 banks, 2-way max (free)
  __shared__ float Vl[64][64];   // lane=d access is bank-parallel
  __shared__ float ql[4][64];

  const u16* qp = qkv + ((size_t)(bb * SEQLEN + qrow)) * D_QKV + h * HEAD_D;
  ql[wv][ln] = b2f(qp[ln]) * 0.125f;         // 1/sqrt(64)

  float o = 0.0f, mrun = -__builtin_inff(), lsum = 0.0f;
  const int nch = qblk / 16 + 1;

  const int srow = threadIdx.x >> 2;         // 0..63
  const int scol = (threadIdx.x & 3) * 16;   // 16 elements each

  for (int c = 0; c < nch; ++c) {
    const int k0 = c * 64;
    const u16* kp = qkv + ((size_t)(bb * SEQLEN + k0 + srow)) * D_QKV + D_MODEL + h * HEAD_D + scol;
    const u16* vp = kp + D_MODEL;
    uint32_t kd[8], vd[8];
    *(uint4*)&kd[0] = ((const uint4*)kp)[0];
    *(uint4*)&kd[4] = ((const uint4*)kp)[1];
    *(uint4*)&vd[0] = ((const uint4*)vp)[0];
    *(uint4*)&vd[4] = ((const uint4*)vp)[1];
#pragma unroll
    for (int j = 0; j < 8; ++j) {
      Kl[srow][scol + 2 * j]     = __uint_as_float(kd[j] << 16);
      Kl[srow][scol + 2 * j + 1] = __uint_as_float(kd[j] & 0xffff0000u);
      Vl[srow][scol + 2 * j]     = __uint_as_float(vd[j] << 16);
      Vl[srow][scol + 2 * j + 1] = __uint_as_float(vd[j] & 0xffff0000u);
    }
    __syncthreads();
    // scores: lane = k index
    float sc = 0.0f;
#pragma unroll 8
    for (int d = 0; d < 64; ++d) sc += ql[wv][d] * Kl[ln][d];
    if (k0 + ln > qrow) sc = -__builtin_inff();
    float mc = sc;
    for (int off = 32; off; off >>= 1) mc = fmaxf(mc, __shfl_xor(mc, off));
    float mnew = fmaxf(mrun, mc);
    float pscale = __expf(mrun - mnew);      // c==0: exp(-inf)=0, o/lsum are 0
    float pv = __expf(sc - mnew);
    lsum = lsum * pscale + pv;
    o *= pscale;
    // PV: lane = d index; broadcast p_k via shuffle
#pragma unroll 8
    for (int k = 0; k < 64; ++k) o += __shfl(pv, k) * Vl[k][ln];
    mrun = mnew;
    __syncthreads();
  }
  for (int off = 32; off; off >>= 1) lsum += __shfl_xor(lsum, off);
  out[((size_t)(bb * SEQLEN + qrow)) * D_MODEL + h * HEAD_D + ln] = f2b(o / lsum);
}

// ---------------- host ----------------
extern "C" void kernel_launch(void* const* d_in, const int* in_sizes, int n_in,
                              void* d_out, int out_size, void* d_ws, size_t ws_size,
                              hipStream_t stream) {
  (void)in_sizes; (void)n_in; (void)out_size; (void)ws_size;
  const int*   ids   = (const int*)d_in[0];
  const float* emb   = (const float*)d_in[1];
  const float* pos   = (const float*)d_in[2];
  const float* ln1w  = (const float*)d_in[3];
  const float* ln1b  = (const float*)d_in[4];
  const float* Wattn = (const float*)d_in[5];
  const float* battn = (const float*)d_in[6];
  const float* WO    = (const float*)d_in[7];
  const float* bO    = (const float*)d_in[8];
  const float* ln2w  = (const float*)d_in[9];
  const float* ln2b  = (const float*)d_in[10];
  const float* Win   = (const float*)d_in[11];
  const float* bin   = (const float*)d_in[12];
  const float* Wout  = (const float*)d_in[13];
  const float* bout  = (const float*)d_in[14];
  const float* lnfw  = (const float*)d_in[15];
  const float* lnfb  = (const float*)d_in[16];
  const float* WU    = (const float*)d_in[17];
  const float* bU    = (const float*)d_in[18];

  char* p = (char*)d_ws;
  auto carve = [&](size_t bytes) {
    char* r = p;
    p += (bytes + 255) & ~(size_t)255;
    return r;
  };
  float* R      = (float*)carve((size_t)N_TOK * D_MODEL * 4);
  u16*   xb     = (u16*)carve((size_t)N_TOK * D_MODEL * 2);
  u16*   qkvb   = (u16*)carve((size_t)N_TOK * D_QKV * 2);
  u16*   attnb  = (u16*)carve((size_t)N_TOK * D_MODEL * 2);
  u16*   hb     = (u16*)carve((size_t)N_TOK * D_FF * 2);
  u16*   Wattnb = (u16*)carve((size_t)N_LAYER * D_QKV * D_MODEL * 2);
  u16*   WOb    = (u16*)carve((size_t)N_LAYER * D_MODEL * D_MODEL * 2);
  u16*   Winb   = (u16*)carve((size_t)N_LAYER * D_FF * D_MODEL * 2);
  u16*   Woutb  = (u16*)carve((size_t)N_LAYER * D_MODEL * D_FF * 2);
  u16*   WUb    = (u16*)carve((size_t)N_VOCAB * D_MODEL * 2);

  auto cvt = [&](const float* s, u16* d, size_t n) {
    int n4 = (int)(n / 4);
    cvt_k<<<dim3((n4 + 255) / 256), dim3(256), 0, stream>>>(s, d, n4);
  };
  cvt(Wattn, Wattnb, (size_t)N_LAYER * D_QKV * D_MODEL);
  cvt(WO,    WOb,    (size_t)N_LAYER * D_MODEL * D_MODEL);
  cvt(Win,   Winb,   (size_t)N_LAYER * D_FF * D_MODEL);
  cvt(Wout,  Woutb,  (size_t)N_LAYER * D_MODEL * D_FF);
  cvt(WU,    WUb,    (size_t)N_VOCAB * D_MODEL);

  embed_k<<<dim3(N_TOK), dim3(256), 0, stream>>>(ids, emb, pos, R);

  for (int l = 0; l < N_LAYER; ++l) {
    ln_k<<<dim3(N_TOK), dim3(256), 0, stream>>>(R, ln1w + l * D_MODEL, ln1b + l * D_MODEL, xb);
    gemm_bt<false, false, true><<<dim3(D_QKV / 128, N_TOK / 128), 256, 0, stream>>>(
        xb, Wattnb + (size_t)l * D_QKV * D_MODEL, battn + l * D_QKV, nullptr,
        qkvb, N_TOK, D_QKV, D_MODEL);
    attn_k<<<dim3(SEQLEN / 4, 2 * N_HEAD), 256, 0, stream>>>(qkvb, attnb);
    gemm_bt<false, true, false><<<dim3(D_MODEL / 128, N_TOK / 128), 256, 0, stream>>>(
        attnb, WOb + (size_t)l * D_MODEL * D_MODEL, bO + l * D_MODEL, R,
        R, N_TOK, D_MODEL, D_MODEL);
    ln_k<<<dim3(N_TOK), dim3(256), 0, stream>>>(R, ln2w + l * D_MODEL, ln2b + l * D_MODEL, xb);
    gemm_bt<true, false, true><<<dim3(D_FF / 128, N_TOK / 128), 256, 0, stream>>>(
        xb, Winb + (size_t)l * D_FF * D_MODEL, bin + l * D_FF, nullptr,
        hb, N_TOK, D_FF, D_MODEL);
    gemm_bt<false, true, false><<<dim3(D_MODEL / 128, N_TOK / 128), 256, 0, stream>>>(
        hb, Woutb + (size_t)l * D_MODEL * D_FF, bout + l * D_MODEL, R,
        R, N_TOK, D_MODEL, D_FF);
  }
  ln_k<<<dim3(N_TOK), dim3(256), 0, stream>>>(R, lnfw, lnfb, xb);
  gemm_bt<false, false, false><<<dim3((N_VOCAB + 127) / 128, N_TOK / 128), 256, 0, stream>>>(
      xb, WUb, bU, nullptr, d_out, N_TOK, N_VOCAB, D_MODEL);
}